// Round 1
// baseline (609.417 us; speedup 1.0000x reference)
//
#include <hip/hip_runtime.h>

// ---------------------------------------------------------------------------
// GNN predictor (fp32 I/O). Round 10 = Round 9 structure plus fused-kernel
// VALU diet:
//   - tanh scale 2*log2(e) folded into W2e/b2e at prep (kills 16 mul/batch)
//   - sum-of-sigmoid transform: sum tanh = deg - 2*sum 1/(1+e)  (kills fma)
//   - pairwise rcp: 1/(1+u0)+1/(1+u1) = (2+q)/(1+q+p)  (32 -> 24 trans/batch)
//   - full/tail batch split: per-element masks only in the tail batch
//   - dynamic node chunking via global cursor (evens wave drain tail)
//   - gcnt memset + cursor zero folded into prep_weights (one less node)
// Round-8's 64KB-LDS bucket fusion REGRESSED 3x; do not re-fuse below
// ~8 waves/CU.
// ---------------------------------------------------------------------------

#define LRELU_SLOPE 0.01f
#define BUCK_SHIFT 8                  // 256 nodes per bucket
#define TANH_SCALE 2.8853900817779268f  // 2*log2(e), folded into W2e/b2e

constexpr int OFF_W1ET  = 0;          // [32][76]  edge W1 transposed
constexpr int OFF_B1E   = 2432;       // [32]
constexpr int OFF_W2E   = 2464;       // [32][64]  (unused; layout kept)
constexpr int OFF_B2E   = 4512;       // [64]      pre-scaled by TANH_SCALE
constexpr int OFF_W1NA  = 4576;       // [32][76]  node W1 (pos,u,h dims) in x76 order
constexpr int OFF_W1NS  = 7008;       // [32][64]  node W1 (sumh dims) transposed
constexpr int OFF_W2N   = 9056;       // [32][64]
constexpr int OFF_B2N   = 11104;      // [64]
constexpr int OFF_B1N   = 11168;      // [32]
constexpr int OFF_W1POS = 11200;      // [32] float2 (W1e rows 2,3)
constexpr int W_TOTAL   = 11264;

typedef __bf16 bf16x8 __attribute__((ext_vector_type(8)));
typedef float  f32x4  __attribute__((ext_vector_type(4)));

__device__ __forceinline__ float ftanh(float x) {
    float e = __builtin_amdgcn_exp2f(x * 2.8853900817779268f);
    return 1.0f - 2.0f * __builtin_amdgcn_rcpf(e + 1.0f);
}
__device__ __forceinline__ unsigned f2bf_pair(float f0, float f1) {
    unsigned u0 = __float_as_uint(f0), u1 = __float_as_uint(f1);
    unsigned r0 = (u0 + 0x7fffu + ((u0 >> 16) & 1u)) >> 16;   // RNE
    unsigned r1 = (u1 + 0x7fffu + ((u1 >> 16) & 1u)) >> 16;
    return r0 | (r1 << 16);
}
__device__ __forceinline__ float bf_lo(unsigned p) { return __uint_as_float(p << 16); }
__device__ __forceinline__ float bf_hi(unsigned p) { return __uint_as_float(p & 0xffff0000u); }

// ---------------------------------------------------------------------------
__global__ void prep_weights(const float* __restrict__ W1e, const float* __restrict__ b1e,
                             const float* __restrict__ W2e, const float* __restrict__ b2e,
                             const float* __restrict__ W1n, const float* __restrict__ b1n,
                             const float* __restrict__ W2n, const float* __restrict__ b2n,
                             float* __restrict__ Wf, uint4* __restrict__ fragW2,
                             int* __restrict__ gcnt, int* __restrict__ cursor, int nbuck) {
    int t = blockIdx.x * blockDim.x + threadIdx.x;
    int T = gridDim.x * blockDim.x;
    if (t == 0) *cursor = 0;
    for (int idx = t; idx < nbuck; idx += T) gcnt[idx] = 0;
    for (int idx = t; idx < 2432; idx += T) {            // W1e [76][32] -> [32][76]
        int i = idx / 32, j = idx % 32;
        Wf[OFF_W1ET + j * 76 + i] = W1e[idx];
    }
    for (int idx = t; idx < 32; idx += T)   Wf[OFF_B1E + idx] = b1e[idx];
    for (int idx = t; idx < 64; idx += T)   Wf[OFF_B2E + idx] = b2e[idx] * TANH_SCALE;
    // W1NA[j][i]: node-layer1 weights for x76 = [pos(2),0,0,u(8),h(64)]
    for (int idx = t; idx < 2432; idx += T) {
        int j = idx / 76, i = idx % 76;
        float v = 0.f;
        if (i < 2)                 v = W1n[i * 32 + j];
        else if (i >= 4 && i < 12) v = W1n[(130 + (i - 4)) * 32 + j];
        else if (i >= 12)          v = W1n[(2 + (i - 12)) * 32 + j];
        Wf[OFF_W1NA + idx] = v;
    }
    for (int idx = t; idx < 2048; idx += T) {            // W1NS [32][64]
        int j = idx / 64, k = idx % 64;
        Wf[OFF_W1NS + idx] = W1n[(66 + k) * 32 + j];
    }
    for (int idx = t; idx < 2048; idx += T) Wf[OFF_W2N + idx] = W2n[idx];
    for (int idx = t; idx < 64; idx += T)   Wf[OFF_B2N + idx] = b2n[idx];
    for (int idx = t; idx < 32; idx += T)   Wf[OFF_B1N + idx] = b1n[idx];
    for (int idx = t; idx < 32; idx += T) {
        Wf[OFF_W1POS + 2 * idx + 0] = W1e[2 * 32 + idx];
        Wf[OFF_W1POS + 2 * idx + 1] = W1e[3 * 32 + idx];
    }
    // MFMA B-fragments for W2e (bf16, pre-scaled), 4 N-tiles x 64 lanes x 16B
    for (int idx = t; idx < 256; idx += T) {
        int tt = idx >> 6, l = idx & 63;
        int colv = l & 15, quadv = l >> 4;
        uint4 v;
        unsigned pk[4];
#pragma unroll
        for (int pr = 0; pr < 4; pr++) {
            int j0 = quadv * 8 + 2 * pr;
            float f0 = W2e[j0 * 64 + 16 * tt + colv] * TANH_SCALE;
            float f1 = W2e[(j0 + 1) * 64 + 16 * tt + colv] * TANH_SCALE;
            pk[pr] = f2bf_pair(f0, f1);
        }
        v.x = pk[0]; v.y = pk[1]; v.z = pk[2]; v.w = pk[3];
        fragW2[tt * 64 + l] = v;
    }
}

// ---------------------------------------------------------------------------
// Phase 1: bucket-scatter (blocks < nblkA) + per-node precompute (rest):
//   Abf[n][32] bf16 : edge-MLP layer1 src part
//   A2 [n][32] f32  : node-MLP layer1 pos/h/u part (+b1n)
// ---------------------------------------------------------------------------
__global__ __launch_bounds__(256) void k_phase1(
    const float* __restrict__ hbuf, const float* __restrict__ ubuf,
    const float* __restrict__ posbuf, const float* __restrict__ Wf,
    uint4* __restrict__ Abf, float* __restrict__ A2,
    const int* __restrict__ src, const int* __restrict__ dst,
    int* __restrict__ gcnt, unsigned* __restrict__ pairbuf,
    int E, int N, int C, int nblkA) {
    __shared__ int cnt[512], base[512];
    int tid = threadIdx.x;
    if ((int)blockIdx.x < nblkA) {
        for (int i = tid; i < 512; i += 256) cnt[i] = 0;
        __syncthreads();
        int e0 = blockIdx.x * 4096;
#pragma unroll
        for (int k = 0; k < 16; k++) {
            int e = e0 + k * 256 + tid;
            if (e < E) atomicAdd(&cnt[dst[e] >> BUCK_SHIFT], 1);
        }
        __syncthreads();
        for (int i = tid; i < 512; i += 256) {
            int c = cnt[i];
            base[i] = (c > 0) ? atomicAdd(&gcnt[i], c) : 0;
            cnt[i] = 0;
        }
        __syncthreads();
#pragma unroll
        for (int k = 0; k < 16; k++) {
            int e = e0 + k * 256 + tid;
            if (e < E) {
                int d = dst[e];
                int b = d >> BUCK_SHIFT;
                int r = base[b] + atomicAdd(&cnt[b], 1);
                if (r < C)
                    pairbuf[(size_t)b * C + r] =
                        (unsigned)src[e] | ((unsigned)(d & 255) << 20);
            }
        }
        return;
    }
    // ---- per-node precompute ----
    int n = (blockIdx.x - nblkA) * 256 + tid;
    if (n >= N) return;
    float x[76];
    float2 pp = ((const float2*)posbuf)[n];
    x[0] = pp.x; x[1] = pp.y; x[2] = 0.f; x[3] = 0.f;
    const float4* u4 = (const float4*)ubuf;
#pragma unroll
    for (int c = 0; c < 2; c++) {
        float4 uu = u4[(size_t)n * 2 + c];
        int b = 4 + 4 * c;
        x[b] = uu.x; x[b + 1] = uu.y; x[b + 2] = uu.z; x[b + 3] = uu.w;
    }
    const float4* h4 = (const float4*)hbuf;
#pragma unroll
    for (int c = 0; c < 16; c++) {
        float4 hh = h4[(size_t)n * 16 + c];
        int b = 12 + 4 * c;
        x[b] = hh.x; x[b + 1] = hh.y; x[b + 2] = hh.z; x[b + 3] = hh.w;
    }
    float ar[32];
#pragma unroll 1
    for (int j = 0; j < 32; j++) {
        const float* w1 = Wf + OFF_W1ET + j * 76;
        float a0 = Wf[OFF_B1E + j], a1 = 0.f, a2 = 0.f, a3 = 0.f;
#pragma unroll
        for (int i = 0; i < 76; i += 4) {
            a0 = fmaf(x[i + 0], w1[i + 0], a0);
            a1 = fmaf(x[i + 1], w1[i + 1], a1);
            a2 = fmaf(x[i + 2], w1[i + 2], a2);
            a3 = fmaf(x[i + 3], w1[i + 3], a3);
        }
        ar[j] = (a0 + a1) + (a2 + a3);
    }
#pragma unroll
    for (int c = 0; c < 4; c++) {
        uint4 v;
        v.x = f2bf_pair(ar[8 * c + 0], ar[8 * c + 1]);
        v.y = f2bf_pair(ar[8 * c + 2], ar[8 * c + 3]);
        v.z = f2bf_pair(ar[8 * c + 4], ar[8 * c + 5]);
        v.w = f2bf_pair(ar[8 * c + 6], ar[8 * c + 7]);
        Abf[(size_t)n * 4 + c] = v;
    }
    // node-MLP layer1 pos/h/u part (x[2],x[3] are zero -> harmless)
#pragma unroll 1
    for (int j = 0; j < 32; j++) {
        const float* w1 = Wf + OFF_W1NA + j * 76;
        float a0 = Wf[OFF_B1N + j], a1 = 0.f, a2 = 0.f, a3 = 0.f;
#pragma unroll
        for (int i = 0; i < 76; i += 4) {
            a0 = fmaf(x[i + 0], w1[i + 0], a0);
            a1 = fmaf(x[i + 1], w1[i + 1], a1);
            a2 = fmaf(x[i + 2], w1[i + 2], a2);
            a3 = fmaf(x[i + 3], w1[i + 3], a3);
        }
        ar[j] = (a0 + a1) + (a2 + a3);
    }
#pragma unroll
    for (int c = 0; c < 8; c++) {
        float4 v; v.x = ar[4 * c]; v.y = ar[4 * c + 1];
        v.z = ar[4 * c + 2]; v.w = ar[4 * c + 3];
        ((float4*)(A2 + (size_t)n * 32))[c] = v;
    }
}

// ---------------------------------------------------------------------------
// Pass B: one block per bucket. LDS deg/scan -> seg; LDS-cursor scatter ssrc.
// ---------------------------------------------------------------------------
__global__ __launch_bounds__(256) void k_bucketB(
    const unsigned* __restrict__ pairbuf, const int* __restrict__ gcnt,
    int2* __restrict__ seg, int* __restrict__ ssrc, int N, int C) {
    __shared__ int deg[256], scn[256], exc[256], cur[256];
    int b = blockIdx.x, tid = threadIdx.x;
    int cntb = gcnt[b];
    cntb = (cntb < C) ? cntb : C;
    deg[tid] = 0; cur[tid] = 0;
    __syncthreads();
    size_t basep = (size_t)b * C;
    for (int i = tid; i < cntb; i += 256)
        atomicAdd(&deg[pairbuf[basep + i] >> 20], 1);
    __syncthreads();
    scn[tid] = deg[tid];
    __syncthreads();
    for (int st = 1; st < 256; st <<= 1) {
        int add = (tid >= st) ? scn[tid - st] : 0;
        __syncthreads();
        scn[tid] += add;
        __syncthreads();
    }
    int ex = scn[tid] - deg[tid];
    exc[tid] = ex;
    int n = (b << BUCK_SHIFT) + tid;
    if (n < N) {
        int lo = b * C + ex;
        seg[n] = make_int2(lo, lo + deg[tid]);
    }
    __syncthreads();
    for (int i = tid; i < cntb; i += 256) {
        unsigned p = pairbuf[basep + i];
        int l = (int)(p >> 20);
        int slot = exc[l] + atomicAdd(&cur[l], 1);
        ssrc[basep + slot] = (int)(p & 0xFFFFFu);
    }
}

// ---------------------------------------------------------------------------
// Fused edge-MLP + gather. sum tanh = deg - 2*sum sigma; weights pre-scaled
// by 2*log2(e) so exp2 takes the MFMA acc directly. Pairwise rcp combine.
// Full batches are mask-free; <=1 masked tail batch per node. Waves pull
// 4-node chunks off a global cursor.
// ---------------------------------------------------------------------------
__global__ __launch_bounds__(256) void fused_edge_gather(
    const int2* __restrict__ seg, const int* __restrict__ ssrc,
    const uint4* __restrict__ Abf, const float* __restrict__ posbuf,
    const float* __restrict__ Wf, const uint4* __restrict__ fragW2,
    float* __restrict__ sumh, int* __restrict__ cursor, int N) {
    int lane = threadIdx.x & 63;
    int col = lane & 15, quad = lane >> 4;

    union { uint4 u; bf16x8 v; } cvt;
    bf16x8 bfr[4];
#pragma unroll
    for (int t = 0; t < 4; t++) {
        cvt.u = fragW2[t * 64 + lane];
        bfr[t] = cvt.v;
    }
    float c0[4];
#pragma unroll
    for (int t = 0; t < 4; t++) c0[t] = Wf[OFF_B2E + 16 * t + col];
    float wx[8], wy[8];
#pragma unroll
    for (int jj = 0; jj < 8; jj++) {
        float2 wv = ((const float2*)(Wf + OFF_W1POS))[quad * 8 + jj];
        wx[jj] = wv.x; wy[jj] = wv.y;
    }

    for (;;) {
        int n0 = 0;
        if (lane == 0) n0 = atomicAdd(cursor, 4);
        n0 = __shfl(n0, 0);
        if (n0 >= N) break;
        int n1 = n0 + 4; n1 = (n1 < N) ? n1 : N;
#pragma unroll 1
        for (int n = n0; n < n1; n++) {
            int2 sg = seg[n];
            int lo = sg.x, hi = sg.y, deg = hi - lo;
            float2 pd = ((const float2*)posbuf)[n];
            float padd[8];
#pragma unroll
            for (int jj = 0; jj < 8; jj++)
                padd[jj] = fmaf(pd.x, wx[jj], pd.y * wy[jj]);

            float s0[4] = {0.f, 0.f, 0.f, 0.f};
            if (deg > 0) {
                int te = lo + col;
                te = (te < hi) ? te : (hi - 1);
                uint4 ar = Abf[(size_t)ssrc[te] * 4 + quad];
                int nfull = deg & ~15;
#pragma unroll 1
                for (int b = 0; b < nfull; b += 16) {
                    // prefetch next batch (clamped)
                    int teN = lo + b + 16 + col;
                    teN = (teN < hi) ? teN : (hi - 1);
                    uint4 arN = Abf[(size_t)ssrc[teN] * 4 + quad];

                    bf16x8 af;
                    {
                        float v0 = bf_lo(ar.x) + padd[0], v1 = bf_hi(ar.x) + padd[1];
                        float v2 = bf_lo(ar.y) + padd[2], v3 = bf_hi(ar.y) + padd[3];
                        float v4 = bf_lo(ar.z) + padd[4], v5 = bf_hi(ar.z) + padd[5];
                        float v6 = bf_lo(ar.w) + padd[6], v7 = bf_hi(ar.w) + padd[7];
                        v0 = fmaxf(v0, LRELU_SLOPE * v0); v1 = fmaxf(v1, LRELU_SLOPE * v1);
                        v2 = fmaxf(v2, LRELU_SLOPE * v2); v3 = fmaxf(v3, LRELU_SLOPE * v3);
                        v4 = fmaxf(v4, LRELU_SLOPE * v4); v5 = fmaxf(v5, LRELU_SLOPE * v5);
                        v6 = fmaxf(v6, LRELU_SLOPE * v6); v7 = fmaxf(v7, LRELU_SLOPE * v7);
                        af[0] = (__bf16)v0; af[1] = (__bf16)v1; af[2] = (__bf16)v2; af[3] = (__bf16)v3;
                        af[4] = (__bf16)v4; af[5] = (__bf16)v5; af[6] = (__bf16)v6; af[7] = (__bf16)v7;
                    }
#pragma unroll
                    for (int t = 0; t < 4; t++) {
                        f32x4 acc = {c0[t], c0[t], c0[t], c0[t]};
                        acc = __builtin_amdgcn_mfma_f32_16x16x32_bf16(af, bfr[t], acc, 0, 0, 0);
                        float u0 = __builtin_amdgcn_exp2f(acc[0]);
                        float u1 = __builtin_amdgcn_exp2f(acc[1]);
                        float u2 = __builtin_amdgcn_exp2f(acc[2]);
                        float u3 = __builtin_amdgcn_exp2f(acc[3]);
                        float q01 = u0 + u1, q23 = u2 + u3;
                        float d01 = fmaf(u0, u1, q01) + 1.f;
                        float d23 = fmaf(u2, u3, q23) + 1.f;
                        s0[t] = fmaf(q01 + 2.f, __builtin_amdgcn_rcpf(d01), s0[t]);
                        s0[t] = fmaf(q23 + 2.f, __builtin_amdgcn_rcpf(d23), s0[t]);
                    }
                    ar = arN;
                }
                int tail = deg - nfull;
                if (tail) {
                    bf16x8 af;
                    {
                        float v0 = bf_lo(ar.x) + padd[0], v1 = bf_hi(ar.x) + padd[1];
                        float v2 = bf_lo(ar.y) + padd[2], v3 = bf_hi(ar.y) + padd[3];
                        float v4 = bf_lo(ar.z) + padd[4], v5 = bf_hi(ar.z) + padd[5];
                        float v6 = bf_lo(ar.w) + padd[6], v7 = bf_hi(ar.w) + padd[7];
                        v0 = fmaxf(v0, LRELU_SLOPE * v0); v1 = fmaxf(v1, LRELU_SLOPE * v1);
                        v2 = fmaxf(v2, LRELU_SLOPE * v2); v3 = fmaxf(v3, LRELU_SLOPE * v3);
                        v4 = fmaxf(v4, LRELU_SLOPE * v4); v5 = fmaxf(v5, LRELU_SLOPE * v5);
                        v6 = fmaxf(v6, LRELU_SLOPE * v6); v7 = fmaxf(v7, LRELU_SLOPE * v7);
                        af[0] = (__bf16)v0; af[1] = (__bf16)v1; af[2] = (__bf16)v2; af[3] = (__bf16)v3;
                        af[4] = (__bf16)v4; af[5] = (__bf16)v5; af[6] = (__bf16)v6; af[7] = (__bf16)v7;
                    }
                    int rowb = quad * 4;
#pragma unroll
                    for (int t = 0; t < 4; t++) {
                        f32x4 acc = {c0[t], c0[t], c0[t], c0[t]};
                        acc = __builtin_amdgcn_mfma_f32_16x16x32_bf16(af, bfr[t], acc, 0, 0, 0);
                        // invalid rows: u = 1e30 -> pair algebra makes the
                        // contribution ~2^-60 (drops out); double-invalid ~0.
                        float u0 = (rowb + 0 < tail) ? __builtin_amdgcn_exp2f(acc[0]) : 1e30f;
                        float u1 = (rowb + 1 < tail) ? __builtin_amdgcn_exp2f(acc[1]) : 1e30f;
                        float u2 = (rowb + 2 < tail) ? __builtin_amdgcn_exp2f(acc[2]) : 1e30f;
                        float u3 = (rowb + 3 < tail) ? __builtin_amdgcn_exp2f(acc[3]) : 1e30f;
                        float q01 = u0 + u1, q23 = u2 + u3;
                        float d01 = fmaf(u0, u1, q01) + 1.f;
                        float d23 = fmaf(u2, u3, q23) + 1.f;
                        s0[t] = fmaf(q01 + 2.f, __builtin_amdgcn_rcpf(d01), s0[t]);
                        s0[t] = fmaf(q23 + 2.f, __builtin_amdgcn_rcpf(d23), s0[t]);
                    }
                }
            }
#pragma unroll
            for (int t = 0; t < 4; t++) {
                s0[t] += __shfl_xor(s0[t], 16);
                s0[t] += __shfl_xor(s0[t], 32);
            }
            if (lane < 16) {
                float* sr = sumh + (size_t)n * 64;
                float fd = (float)deg;
#pragma unroll
                for (int t = 0; t < 4; t++) sr[16 * t + lane] = fmaf(-2.f, s0[t], fd);
            }
        }
    }
}

// ---------------------------------------------------------------------------
// Node kernel (factored): y = A2[n] + W1NS^T . sumh[n]; o = W2n^T . lrelu(y)
// ---------------------------------------------------------------------------
__global__ __launch_bounds__(256) void k_node2(
    const float* __restrict__ A2, const float* __restrict__ sumh,
    const float* __restrict__ Wf, float* __restrict__ out, int N) {
    int n = blockIdx.x * blockDim.x + threadIdx.x;
    if (n >= N) return;

    float s[64];
    const float4* s4 = (const float4*)(sumh + (size_t)n * 64);
#pragma unroll
    for (int c = 0; c < 16; c++) {
        float4 v = s4[c];
        s[4 * c] = v.x; s[4 * c + 1] = v.y; s[4 * c + 2] = v.z; s[4 * c + 3] = v.w;
    }

    float o[64];
#pragma unroll
    for (int k = 0; k < 64; k++) o[k] = Wf[OFF_B2N + k];

    const float4* a24 = (const float4*)(A2 + (size_t)n * 32);
#pragma unroll 1
    for (int jj = 0; jj < 8; jj++) {
        float4 av = a24[jj];
#pragma unroll
        for (int q = 0; q < 4; q++) {
            int j = jj * 4 + q;
            const float* w1 = Wf + OFF_W1NS + j * 64;   // uniform -> s_load
            float a0 = (q == 0) ? av.x : (q == 1) ? av.y : (q == 2) ? av.z : av.w;
            float a1 = 0.f, a2 = 0.f, a3 = 0.f;
#pragma unroll
            for (int i = 0; i < 64; i += 4) {
                a0 = fmaf(s[i + 0], w1[i + 0], a0);
                a1 = fmaf(s[i + 1], w1[i + 1], a1);
                a2 = fmaf(s[i + 2], w1[i + 2], a2);
                a3 = fmaf(s[i + 3], w1[i + 3], a3);
            }
            float y = (a0 + a1) + (a2 + a3);
            y = (y >= 0.f) ? y : LRELU_SLOPE * y;
            const float* w2 = Wf + OFF_W2N + j * 64;    // uniform -> s_load
#pragma unroll
            for (int k = 0; k < 64; k++) o[k] = fmaf(y, w2[k], o[k]);
        }
    }

    float4* orow = (float4*)(out + (size_t)n * 64);
#pragma unroll
    for (int c = 0; c < 16; c++) {
        float4 v;
        v.x = ftanh(o[4 * c + 0]); v.y = ftanh(o[4 * c + 1]);
        v.z = ftanh(o[4 * c + 2]); v.w = ftanh(o[4 * c + 3]);
        orow[c] = v;
    }
}

// ---------------------------------------------------------------------------
extern "C" void kernel_launch(void* const* d_in, const int* in_sizes, int n_in,
                              void* d_out, int out_size, void* d_ws, size_t ws_size,
                              hipStream_t stream) {
    const float* hbuf   = (const float*)d_in[0];
    const float* ubuf   = (const float*)d_in[1];
    const float* posbuf = (const float*)d_in[2];
    const int* src = (const int*)d_in[3];
    const int* dst = (const int*)d_in[4];

    int N = in_sizes[0] / 64;
    int E = in_sizes[3];
    int NBUCK = (N + 255) >> BUCK_SHIFT;                 // 256-node buckets
    int C = ((2 * ((E + NBUCK - 1) / NBUCK)) + 255) & ~255;  // bucket capacity
    int nblkA = (E + 4095) / 4096;

    char* p = (char*)d_ws;
    auto alloc = [&](size_t bytes) {
        char* r = p;
        p += (bytes + 255) & ~(size_t)255;
        return r;
    };
    float*    Wf      = (float*)alloc(W_TOTAL * 4);
    uint4*    fragW2  = (uint4*)alloc(4 * 64 * 16);
    uint4*    Abf     = (uint4*)alloc((size_t)N * 64);   // bf16 A rows, 64B
    float*    A2      = (float*)alloc((size_t)N * 32 * 4);
    float*    sumh    = (float*)alloc((size_t)N * 64 * 4);
    int2*     seg     = (int2*)alloc((size_t)N * 8);
    int*      gcnt    = (int*)alloc((size_t)NBUCK * 4);
    int*      cursor  = (int*)alloc(256);
    unsigned* pairbuf = (unsigned*)alloc((size_t)NBUCK * C * 4);
    int*      ssrc    = (int*)alloc((size_t)NBUCK * C * 4);

    prep_weights<<<32, 256, 0, stream>>>(
        (const float*)d_in[5], (const float*)d_in[6],
        (const float*)d_in[7], (const float*)d_in[8],
        (const float*)d_in[9], (const float*)d_in[10],
        (const float*)d_in[11], (const float*)d_in[12], Wf, fragW2,
        gcnt, cursor, NBUCK);

    int nblkP = nblkA + (N + 255) / 256;
    k_phase1<<<nblkP, 256, 0, stream>>>(
        hbuf, ubuf, posbuf, Wf, Abf, A2, src, dst, gcnt, pairbuf, E, N, C, nblkA);

    k_bucketB<<<NBUCK, 256, 0, stream>>>(pairbuf, gcnt, seg, ssrc, N, C);

    const int FBLK = 2048;                    // 8192 waves = full machine
    fused_edge_gather<<<FBLK, 256, 0, stream>>>(
        seg, ssrc, Abf, posbuf, Wf, fragW2, sumh, cursor, N);

    k_node2<<<(N + 255) / 256, 256, 0, stream>>>(
        A2, sumh, Wf, (float*)d_out, N);
}

// Round 2
// 285.533 us; speedup vs baseline: 2.1343x; 2.1343x over previous
//
#include <hip/hip_runtime.h>

// ---------------------------------------------------------------------------
// GNN predictor (fp32 I/O). Round 11 = Round 9 structure (static per-wave
// node partition; best measured: fused=85.8us, total=306.7us) plus the
// Round-10 VALU diet (which was sound):
//   - tanh scale 2*log2(e) folded into W2e/b2e at prep (kills 16 mul/batch)
//   - sum-of-sigmoid transform: sum tanh = deg - 2*sum 1/(1+e)  (kills fma)
//   - pairwise rcp: 1/(1+u0)+1/(1+u1) = (2+q)/(1+q+p)  (16 -> 8 rcp/batch)
//   - full/tail batch split: per-element masks only in the tail batch
//   - gcnt memset folded into prep_weights (one less graph node)
// Round-10 LESSON: single global-cursor dynamic chunking REGRESSED 4.5x
// (25000 same-line device atomics serialize at the owning L2; waves sit
// idle: VALUBusy 68->12%). dst is uniform-random => static 13-node/wave
// partition has only +/-7% Poisson imbalance. DO NOT re-add a global cursor.
// Round-8 LESSON: 64KB-LDS bucket fusion regressed 3x; do not re-fuse
// below ~8 waves/CU.
// ---------------------------------------------------------------------------

#define LRELU_SLOPE 0.01f
#define BUCK_SHIFT 8                  // 256 nodes per bucket
#define TANH_SCALE 2.8853900817779268f  // 2*log2(e), folded into W2e/b2e

constexpr int OFF_W1ET  = 0;          // [32][76]  edge W1 transposed
constexpr int OFF_B1E   = 2432;       // [32]
constexpr int OFF_W2E   = 2464;       // [32][64]  (unused; layout kept)
constexpr int OFF_B2E   = 4512;       // [64]      pre-scaled by TANH_SCALE
constexpr int OFF_W1NA  = 4576;       // [32][76]  node W1 (pos,u,h dims) in x76 order
constexpr int OFF_W1NS  = 7008;       // [32][64]  node W1 (sumh dims) transposed
constexpr int OFF_W2N   = 9056;       // [32][64]
constexpr int OFF_B2N   = 11104;      // [64]
constexpr int OFF_B1N   = 11168;      // [32]
constexpr int OFF_W1POS = 11200;      // [32] float2 (W1e rows 2,3)
constexpr int W_TOTAL   = 11264;

typedef __bf16 bf16x8 __attribute__((ext_vector_type(8)));
typedef float  f32x4  __attribute__((ext_vector_type(4)));

__device__ __forceinline__ float ftanh(float x) {
    float e = __builtin_amdgcn_exp2f(x * 2.8853900817779268f);
    return 1.0f - 2.0f * __builtin_amdgcn_rcpf(e + 1.0f);
}
__device__ __forceinline__ unsigned f2bf_pair(float f0, float f1) {
    unsigned u0 = __float_as_uint(f0), u1 = __float_as_uint(f1);
    unsigned r0 = (u0 + 0x7fffu + ((u0 >> 16) & 1u)) >> 16;   // RNE
    unsigned r1 = (u1 + 0x7fffu + ((u1 >> 16) & 1u)) >> 16;
    return r0 | (r1 << 16);
}
__device__ __forceinline__ float bf_lo(unsigned p) { return __uint_as_float(p << 16); }
__device__ __forceinline__ float bf_hi(unsigned p) { return __uint_as_float(p & 0xffff0000u); }

// ---------------------------------------------------------------------------
__global__ void prep_weights(const float* __restrict__ W1e, const float* __restrict__ b1e,
                             const float* __restrict__ W2e, const float* __restrict__ b2e,
                             const float* __restrict__ W1n, const float* __restrict__ b1n,
                             const float* __restrict__ W2n, const float* __restrict__ b2n,
                             float* __restrict__ Wf, uint4* __restrict__ fragW2,
                             int* __restrict__ gcnt, int nbuck) {
    int t = blockIdx.x * blockDim.x + threadIdx.x;
    int T = gridDim.x * blockDim.x;
    for (int idx = t; idx < nbuck; idx += T) gcnt[idx] = 0;
    for (int idx = t; idx < 2432; idx += T) {            // W1e [76][32] -> [32][76]
        int i = idx / 32, j = idx % 32;
        Wf[OFF_W1ET + j * 76 + i] = W1e[idx];
    }
    for (int idx = t; idx < 32; idx += T)   Wf[OFF_B1E + idx] = b1e[idx];
    for (int idx = t; idx < 64; idx += T)   Wf[OFF_B2E + idx] = b2e[idx] * TANH_SCALE;
    // W1NA[j][i]: node-layer1 weights for x76 = [pos(2),0,0,u(8),h(64)]
    for (int idx = t; idx < 2432; idx += T) {
        int j = idx / 76, i = idx % 76;
        float v = 0.f;
        if (i < 2)                 v = W1n[i * 32 + j];
        else if (i >= 4 && i < 12) v = W1n[(130 + (i - 4)) * 32 + j];
        else if (i >= 12)          v = W1n[(2 + (i - 12)) * 32 + j];
        Wf[OFF_W1NA + idx] = v;
    }
    for (int idx = t; idx < 2048; idx += T) {            // W1NS [32][64]
        int j = idx / 64, k = idx % 64;
        Wf[OFF_W1NS + idx] = W1n[(66 + k) * 32 + j];
    }
    for (int idx = t; idx < 2048; idx += T) Wf[OFF_W2N + idx] = W2n[idx];
    for (int idx = t; idx < 64; idx += T)   Wf[OFF_B2N + idx] = b2n[idx];
    for (int idx = t; idx < 32; idx += T)   Wf[OFF_B1N + idx] = b1n[idx];
    for (int idx = t; idx < 32; idx += T) {
        Wf[OFF_W1POS + 2 * idx + 0] = W1e[2 * 32 + idx];
        Wf[OFF_W1POS + 2 * idx + 1] = W1e[3 * 32 + idx];
    }
    // MFMA B-fragments for W2e (bf16, pre-scaled), 4 N-tiles x 64 lanes x 16B
    for (int idx = t; idx < 256; idx += T) {
        int tt = idx >> 6, l = idx & 63;
        int colv = l & 15, quadv = l >> 4;
        uint4 v;
        unsigned pk[4];
#pragma unroll
        for (int pr = 0; pr < 4; pr++) {
            int j0 = quadv * 8 + 2 * pr;
            float f0 = W2e[j0 * 64 + 16 * tt + colv] * TANH_SCALE;
            float f1 = W2e[(j0 + 1) * 64 + 16 * tt + colv] * TANH_SCALE;
            pk[pr] = f2bf_pair(f0, f1);
        }
        v.x = pk[0]; v.y = pk[1]; v.z = pk[2]; v.w = pk[3];
        fragW2[tt * 64 + l] = v;
    }
}

// ---------------------------------------------------------------------------
// Phase 1: bucket-scatter (blocks < nblkA) + per-node precompute (rest):
//   Abf[n][32] bf16 : edge-MLP layer1 src part
//   A2 [n][32] f32  : node-MLP layer1 pos/h/u part (+b1n)
// ---------------------------------------------------------------------------
__global__ __launch_bounds__(256) void k_phase1(
    const float* __restrict__ hbuf, const float* __restrict__ ubuf,
    const float* __restrict__ posbuf, const float* __restrict__ Wf,
    uint4* __restrict__ Abf, float* __restrict__ A2,
    const int* __restrict__ src, const int* __restrict__ dst,
    int* __restrict__ gcnt, unsigned* __restrict__ pairbuf,
    int E, int N, int C, int nblkA) {
    __shared__ int cnt[512], base[512];
    int tid = threadIdx.x;
    if ((int)blockIdx.x < nblkA) {
        for (int i = tid; i < 512; i += 256) cnt[i] = 0;
        __syncthreads();
        int e0 = blockIdx.x * 4096;
#pragma unroll
        for (int k = 0; k < 16; k++) {
            int e = e0 + k * 256 + tid;
            if (e < E) atomicAdd(&cnt[dst[e] >> BUCK_SHIFT], 1);
        }
        __syncthreads();
        for (int i = tid; i < 512; i += 256) {
            int c = cnt[i];
            base[i] = (c > 0) ? atomicAdd(&gcnt[i], c) : 0;
            cnt[i] = 0;
        }
        __syncthreads();
#pragma unroll
        for (int k = 0; k < 16; k++) {
            int e = e0 + k * 256 + tid;
            if (e < E) {
                int d = dst[e];
                int b = d >> BUCK_SHIFT;
                int r = base[b] + atomicAdd(&cnt[b], 1);
                if (r < C)
                    pairbuf[(size_t)b * C + r] =
                        (unsigned)src[e] | ((unsigned)(d & 255) << 20);
            }
        }
        return;
    }
    // ---- per-node precompute ----
    int n = (blockIdx.x - nblkA) * 256 + tid;
    if (n >= N) return;
    float x[76];
    float2 pp = ((const float2*)posbuf)[n];
    x[0] = pp.x; x[1] = pp.y; x[2] = 0.f; x[3] = 0.f;
    const float4* u4 = (const float4*)ubuf;
#pragma unroll
    for (int c = 0; c < 2; c++) {
        float4 uu = u4[(size_t)n * 2 + c];
        int b = 4 + 4 * c;
        x[b] = uu.x; x[b + 1] = uu.y; x[b + 2] = uu.z; x[b + 3] = uu.w;
    }
    const float4* h4 = (const float4*)hbuf;
#pragma unroll
    for (int c = 0; c < 16; c++) {
        float4 hh = h4[(size_t)n * 16 + c];
        int b = 12 + 4 * c;
        x[b] = hh.x; x[b + 1] = hh.y; x[b + 2] = hh.z; x[b + 3] = hh.w;
    }
    float ar[32];
#pragma unroll 1
    for (int j = 0; j < 32; j++) {
        const float* w1 = Wf + OFF_W1ET + j * 76;
        float a0 = Wf[OFF_B1E + j], a1 = 0.f, a2 = 0.f, a3 = 0.f;
#pragma unroll
        for (int i = 0; i < 76; i += 4) {
            a0 = fmaf(x[i + 0], w1[i + 0], a0);
            a1 = fmaf(x[i + 1], w1[i + 1], a1);
            a2 = fmaf(x[i + 2], w1[i + 2], a2);
            a3 = fmaf(x[i + 3], w1[i + 3], a3);
        }
        ar[j] = (a0 + a1) + (a2 + a3);
    }
#pragma unroll
    for (int c = 0; c < 4; c++) {
        uint4 v;
        v.x = f2bf_pair(ar[8 * c + 0], ar[8 * c + 1]);
        v.y = f2bf_pair(ar[8 * c + 2], ar[8 * c + 3]);
        v.z = f2bf_pair(ar[8 * c + 4], ar[8 * c + 5]);
        v.w = f2bf_pair(ar[8 * c + 6], ar[8 * c + 7]);
        Abf[(size_t)n * 4 + c] = v;
    }
    // node-MLP layer1 pos/h/u part (x[2],x[3] are zero -> harmless)
#pragma unroll 1
    for (int j = 0; j < 32; j++) {
        const float* w1 = Wf + OFF_W1NA + j * 76;
        float a0 = Wf[OFF_B1N + j], a1 = 0.f, a2 = 0.f, a3 = 0.f;
#pragma unroll
        for (int i = 0; i < 76; i += 4) {
            a0 = fmaf(x[i + 0], w1[i + 0], a0);
            a1 = fmaf(x[i + 1], w1[i + 1], a1);
            a2 = fmaf(x[i + 2], w1[i + 2], a2);
            a3 = fmaf(x[i + 3], w1[i + 3], a3);
        }
        ar[j] = (a0 + a1) + (a2 + a3);
    }
#pragma unroll
    for (int c = 0; c < 8; c++) {
        float4 v; v.x = ar[4 * c]; v.y = ar[4 * c + 1];
        v.z = ar[4 * c + 2]; v.w = ar[4 * c + 3];
        ((float4*)(A2 + (size_t)n * 32))[c] = v;
    }
}

// ---------------------------------------------------------------------------
// Pass B: one block per bucket. LDS deg/scan -> seg; LDS-cursor scatter ssrc.
// ---------------------------------------------------------------------------
__global__ __launch_bounds__(256) void k_bucketB(
    const unsigned* __restrict__ pairbuf, const int* __restrict__ gcnt,
    int2* __restrict__ seg, int* __restrict__ ssrc, int N, int C) {
    __shared__ int deg[256], scn[256], exc[256], cur[256];
    int b = blockIdx.x, tid = threadIdx.x;
    int cntb = gcnt[b];
    cntb = (cntb < C) ? cntb : C;
    deg[tid] = 0; cur[tid] = 0;
    __syncthreads();
    size_t basep = (size_t)b * C;
    for (int i = tid; i < cntb; i += 256)
        atomicAdd(&deg[pairbuf[basep + i] >> 20], 1);
    __syncthreads();
    scn[tid] = deg[tid];
    __syncthreads();
    for (int st = 1; st < 256; st <<= 1) {
        int add = (tid >= st) ? scn[tid - st] : 0;
        __syncthreads();
        scn[tid] += add;
        __syncthreads();
    }
    int ex = scn[tid] - deg[tid];
    exc[tid] = ex;
    int n = (b << BUCK_SHIFT) + tid;
    if (n < N) {
        int lo = b * C + ex;
        seg[n] = make_int2(lo, lo + deg[tid]);
    }
    __syncthreads();
    for (int i = tid; i < cntb; i += 256) {
        unsigned p = pairbuf[basep + i];
        int l = (int)(p >> 20);
        int slot = exc[l] + atomicAdd(&cur[l], 1);
        ssrc[basep + slot] = (int)(p & 0xFFFFFu);
    }
}

// ---------------------------------------------------------------------------
// Fused edge-MLP + gather: each wave owns a contiguous node range; manual
// prefetch of next batch's ssrc/Abf overlaps the dependent-load chain with
// the current batch's MFMA + sigmoid-sum epilogue.
// sum tanh = deg - 2*sum sigma; W2e/b2e pre-scaled by 2*log2(e) so exp2
// takes the MFMA acc directly; pairwise rcp halves the rcp count; full
// batches are mask-free (only the <=1 tail batch per node masks rows).
// ---------------------------------------------------------------------------
__global__ __launch_bounds__(256) void fused_edge_gather(
    const int2* __restrict__ seg, const int* __restrict__ ssrc,
    const uint4* __restrict__ Abf, const float* __restrict__ posbuf,
    const float* __restrict__ Wf, const uint4* __restrict__ fragW2,
    float* __restrict__ sumh, int N, int npw) {
    int wid = blockIdx.x * 4 + (threadIdx.x >> 6);
    int lane = threadIdx.x & 63;
    int col = lane & 15, quad = lane >> 4;

    union { uint4 u; bf16x8 v; } cvt;
    bf16x8 bfr[4];
#pragma unroll
    for (int t = 0; t < 4; t++) {
        cvt.u = fragW2[t * 64 + lane];
        bfr[t] = cvt.v;
    }
    float c0[4];
#pragma unroll
    for (int t = 0; t < 4; t++) c0[t] = Wf[OFF_B2E + 16 * t + col];
    float wx[8], wy[8];
#pragma unroll
    for (int jj = 0; jj < 8; jj++) {
        float2 wv = ((const float2*)(Wf + OFF_W1POS))[quad * 8 + jj];
        wx[jj] = wv.x; wy[jj] = wv.y;
    }

    int n0 = wid * npw;
    int n1 = n0 + npw; n1 = (n1 < N) ? n1 : N;
#pragma unroll 1
    for (int n = n0; n < n1; n++) {
        int2 sg = seg[n];
        int lo = sg.x, hi = sg.y, deg = hi - lo;
        float2 pd = ((const float2*)posbuf)[n];
        float padd[8];
#pragma unroll
        for (int jj = 0; jj < 8; jj++)
            padd[jj] = fmaf(pd.x, wx[jj], pd.y * wy[jj]);

        float s0[4] = {0.f, 0.f, 0.f, 0.f};
        if (deg > 0) {
            int te = lo + col;
            te = (te < hi) ? te : (hi - 1);
            uint4 ar = Abf[(size_t)ssrc[te] * 4 + quad];
            int nfull = deg & ~15;
#pragma unroll 1
            for (int b = 0; b < nfull; b += 16) {
                // prefetch next batch (clamped; harmless re-read at the end)
                int teN = lo + b + 16 + col;
                teN = (teN < hi) ? teN : (hi - 1);
                uint4 arN = Abf[(size_t)ssrc[teN] * 4 + quad];

                bf16x8 af;
                {
                    float v0 = bf_lo(ar.x) + padd[0], v1 = bf_hi(ar.x) + padd[1];
                    float v2 = bf_lo(ar.y) + padd[2], v3 = bf_hi(ar.y) + padd[3];
                    float v4 = bf_lo(ar.z) + padd[4], v5 = bf_hi(ar.z) + padd[5];
                    float v6 = bf_lo(ar.w) + padd[6], v7 = bf_hi(ar.w) + padd[7];
                    v0 = fmaxf(v0, LRELU_SLOPE * v0); v1 = fmaxf(v1, LRELU_SLOPE * v1);
                    v2 = fmaxf(v2, LRELU_SLOPE * v2); v3 = fmaxf(v3, LRELU_SLOPE * v3);
                    v4 = fmaxf(v4, LRELU_SLOPE * v4); v5 = fmaxf(v5, LRELU_SLOPE * v5);
                    v6 = fmaxf(v6, LRELU_SLOPE * v6); v7 = fmaxf(v7, LRELU_SLOPE * v7);
                    af[0] = (__bf16)v0; af[1] = (__bf16)v1; af[2] = (__bf16)v2; af[3] = (__bf16)v3;
                    af[4] = (__bf16)v4; af[5] = (__bf16)v5; af[6] = (__bf16)v6; af[7] = (__bf16)v7;
                }
#pragma unroll
                for (int t = 0; t < 4; t++) {
                    f32x4 acc = {c0[t], c0[t], c0[t], c0[t]};
                    acc = __builtin_amdgcn_mfma_f32_16x16x32_bf16(af, bfr[t], acc, 0, 0, 0);
                    float u0 = __builtin_amdgcn_exp2f(acc[0]);
                    float u1 = __builtin_amdgcn_exp2f(acc[1]);
                    float u2 = __builtin_amdgcn_exp2f(acc[2]);
                    float u3 = __builtin_amdgcn_exp2f(acc[3]);
                    float q01 = u0 + u1, q23 = u2 + u3;
                    float d01 = fmaf(u0, u1, q01) + 1.f;
                    float d23 = fmaf(u2, u3, q23) + 1.f;
                    s0[t] = fmaf(q01 + 2.f, __builtin_amdgcn_rcpf(d01), s0[t]);
                    s0[t] = fmaf(q23 + 2.f, __builtin_amdgcn_rcpf(d23), s0[t]);
                }
                ar = arN;
            }
            int tail = deg - nfull;
            if (tail) {
                bf16x8 af;
                {
                    float v0 = bf_lo(ar.x) + padd[0], v1 = bf_hi(ar.x) + padd[1];
                    float v2 = bf_lo(ar.y) + padd[2], v3 = bf_hi(ar.y) + padd[3];
                    float v4 = bf_lo(ar.z) + padd[4], v5 = bf_hi(ar.z) + padd[5];
                    float v6 = bf_lo(ar.w) + padd[6], v7 = bf_hi(ar.w) + padd[7];
                    v0 = fmaxf(v0, LRELU_SLOPE * v0); v1 = fmaxf(v1, LRELU_SLOPE * v1);
                    v2 = fmaxf(v2, LRELU_SLOPE * v2); v3 = fmaxf(v3, LRELU_SLOPE * v3);
                    v4 = fmaxf(v4, LRELU_SLOPE * v4); v5 = fmaxf(v5, LRELU_SLOPE * v5);
                    v6 = fmaxf(v6, LRELU_SLOPE * v6); v7 = fmaxf(v7, LRELU_SLOPE * v7);
                    af[0] = (__bf16)v0; af[1] = (__bf16)v1; af[2] = (__bf16)v2; af[3] = (__bf16)v3;
                    af[4] = (__bf16)v4; af[5] = (__bf16)v5; af[6] = (__bf16)v6; af[7] = (__bf16)v7;
                }
                int rowb = quad * 4;
#pragma unroll
                for (int t = 0; t < 4; t++) {
                    f32x4 acc = {c0[t], c0[t], c0[t], c0[t]};
                    acc = __builtin_amdgcn_mfma_f32_16x16x32_bf16(af, bfr[t], acc, 0, 0, 0);
                    // invalid rows: u = 1e30 -> pair algebra makes the
                    // contribution ~2^-60 (drops out); double-invalid ~0.
                    float u0 = (rowb + 0 < tail) ? __builtin_amdgcn_exp2f(acc[0]) : 1e30f;
                    float u1 = (rowb + 1 < tail) ? __builtin_amdgcn_exp2f(acc[1]) : 1e30f;
                    float u2 = (rowb + 2 < tail) ? __builtin_amdgcn_exp2f(acc[2]) : 1e30f;
                    float u3 = (rowb + 3 < tail) ? __builtin_amdgcn_exp2f(acc[3]) : 1e30f;
                    float q01 = u0 + u1, q23 = u2 + u3;
                    float d01 = fmaf(u0, u1, q01) + 1.f;
                    float d23 = fmaf(u2, u3, q23) + 1.f;
                    s0[t] = fmaf(q01 + 2.f, __builtin_amdgcn_rcpf(d01), s0[t]);
                    s0[t] = fmaf(q23 + 2.f, __builtin_amdgcn_rcpf(d23), s0[t]);
                }
            }
        }
#pragma unroll
        for (int t = 0; t < 4; t++) {
            s0[t] += __shfl_xor(s0[t], 16);
            s0[t] += __shfl_xor(s0[t], 32);
        }
        if (lane < 16) {
            float* sr = sumh + (size_t)n * 64;
            float fd = (float)deg;
#pragma unroll
            for (int t = 0; t < 4; t++) sr[16 * t + lane] = fmaf(-2.f, s0[t], fd);
        }
    }
}

// ---------------------------------------------------------------------------
// Node kernel (factored): y = A2[n] + W1NS^T . sumh[n]; o = W2n^T . lrelu(y)
// ---------------------------------------------------------------------------
__global__ __launch_bounds__(256) void k_node2(
    const float* __restrict__ A2, const float* __restrict__ sumh,
    const float* __restrict__ Wf, float* __restrict__ out, int N) {
    int n = blockIdx.x * blockDim.x + threadIdx.x;
    if (n >= N) return;

    float s[64];
    const float4* s4 = (const float4*)(sumh + (size_t)n * 64);
#pragma unroll
    for (int c = 0; c < 16; c++) {
        float4 v = s4[c];
        s[4 * c] = v.x; s[4 * c + 1] = v.y; s[4 * c + 2] = v.z; s[4 * c + 3] = v.w;
    }

    float o[64];
#pragma unroll
    for (int k = 0; k < 64; k++) o[k] = Wf[OFF_B2N + k];

    const float4* a24 = (const float4*)(A2 + (size_t)n * 32);
#pragma unroll 1
    for (int jj = 0; jj < 8; jj++) {
        float4 av = a24[jj];
#pragma unroll
        for (int q = 0; q < 4; q++) {
            int j = jj * 4 + q;
            const float* w1 = Wf + OFF_W1NS + j * 64;   // uniform -> s_load
            float a0 = (q == 0) ? av.x : (q == 1) ? av.y : (q == 2) ? av.z : av.w;
            float a1 = 0.f, a2 = 0.f, a3 = 0.f;
#pragma unroll
            for (int i = 0; i < 64; i += 4) {
                a0 = fmaf(s[i + 0], w1[i + 0], a0);
                a1 = fmaf(s[i + 1], w1[i + 1], a1);
                a2 = fmaf(s[i + 2], w1[i + 2], a2);
                a3 = fmaf(s[i + 3], w1[i + 3], a3);
            }
            float y = (a0 + a1) + (a2 + a3);
            y = (y >= 0.f) ? y : LRELU_SLOPE * y;
            const float* w2 = Wf + OFF_W2N + j * 64;    // uniform -> s_load
#pragma unroll
            for (int k = 0; k < 64; k++) o[k] = fmaf(y, w2[k], o[k]);
        }
    }

    float4* orow = (float4*)(out + (size_t)n * 64);
#pragma unroll
    for (int c = 0; c < 16; c++) {
        float4 v;
        v.x = ftanh(o[4 * c + 0]); v.y = ftanh(o[4 * c + 1]);
        v.z = ftanh(o[4 * c + 2]); v.w = ftanh(o[4 * c + 3]);
        orow[c] = v;
    }
}

// ---------------------------------------------------------------------------
extern "C" void kernel_launch(void* const* d_in, const int* in_sizes, int n_in,
                              void* d_out, int out_size, void* d_ws, size_t ws_size,
                              hipStream_t stream) {
    const float* hbuf   = (const float*)d_in[0];
    const float* ubuf   = (const float*)d_in[1];
    const float* posbuf = (const float*)d_in[2];
    const int* src = (const int*)d_in[3];
    const int* dst = (const int*)d_in[4];

    int N = in_sizes[0] / 64;
    int E = in_sizes[3];
    int NBUCK = (N + 255) >> BUCK_SHIFT;                 // 256-node buckets
    int C = ((2 * ((E + NBUCK - 1) / NBUCK)) + 255) & ~255;  // bucket capacity
    int nblkA = (E + 4095) / 4096;

    char* p = (char*)d_ws;
    auto alloc = [&](size_t bytes) {
        char* r = p;
        p += (bytes + 255) & ~(size_t)255;
        return r;
    };
    float*    Wf      = (float*)alloc(W_TOTAL * 4);
    uint4*    fragW2  = (uint4*)alloc(4 * 64 * 16);
    uint4*    Abf     = (uint4*)alloc((size_t)N * 64);   // bf16 A rows, 64B
    float*    A2      = (float*)alloc((size_t)N * 32 * 4);
    float*    sumh    = (float*)alloc((size_t)N * 64 * 4);
    int2*     seg     = (int2*)alloc((size_t)N * 8);
    int*      gcnt    = (int*)alloc((size_t)NBUCK * 4);
    unsigned* pairbuf = (unsigned*)alloc((size_t)NBUCK * C * 4);
    int*      ssrc    = (int*)alloc((size_t)NBUCK * C * 4);

    prep_weights<<<32, 256, 0, stream>>>(
        (const float*)d_in[5], (const float*)d_in[6],
        (const float*)d_in[7], (const float*)d_in[8],
        (const float*)d_in[9], (const float*)d_in[10],
        (const float*)d_in[11], (const float*)d_in[12], Wf, fragW2,
        gcnt, NBUCK);

    int nblkP = nblkA + (N + 255) / 256;
    k_phase1<<<nblkP, 256, 0, stream>>>(
        hbuf, ubuf, posbuf, Wf, Abf, A2, src, dst, gcnt, pairbuf, E, N, C, nblkA);

    k_bucketB<<<NBUCK, 256, 0, stream>>>(pairbuf, gcnt, seg, ssrc, N, C);

    const int FBLK = 2048;                    // 8192 waves = full machine
    int npw = (N + FBLK * 4 - 1) / (FBLK * 4);
    fused_edge_gather<<<FBLK, 256, 0, stream>>>(
        seg, ssrc, Abf, posbuf, Wf, fragW2, sumh, N, npw);

    k_node2<<<(N + 255) / 256, 256, 0, stream>>>(
        A2, sumh, Wf, (float*)d_out, N);
}